// Round 16
// baseline (187.108 us; speedup 1.0000x reference)
//
#include <hip/hip_runtime.h>

// Problem constants
#define N_TOK 2304
#define CDIM  1280
#define NH    8
#define DH    160
#define NKT   36          // N_TOK / 64  (u64 bitmask words per row)
#define SCALE 0.07905694150420949f   // 1/sqrt(160)
#define LOG2E 1.4426950408889634f

// Fragment-major buffer geometry (bytes)
#define FRAG_BH   737280     // 160*2304*2 per (b,h)
#define KCH_STR   10240      // 10 ks-chunks of 1KB per 32-key (or 32-q) tile
#define VCH_STR   5120       // 5 dt-chunks of 1KB per 16-key step

typedef __attribute__((ext_vector_type(8))) short bf16x8;
typedef __attribute__((ext_vector_type(4))) float f32x4;
typedef __attribute__((ext_vector_type(16))) float f32x16;

#define MFMA16(a, b, c) __builtin_amdgcn_mfma_f32_16x16x32_bf16((a), (b), (c), 0, 0, 0)
#define MFMA32(a, b, c) __builtin_amdgcn_mfma_f32_32x32x16_bf16((a), (b), (c), 0, 0, 0)

static __device__ __forceinline__ unsigned short f2bf(float f) {
  // round-to-nearest-even f32 -> bf16 (finite inputs only)
  unsigned int u = __builtin_bit_cast(unsigned int, f);
  u += 0x7fffu + ((u >> 16) & 1u);
  return (unsigned short)(u >> 16);
}

static __device__ __forceinline__ float fexp2(float x) {
#if __has_builtin(__builtin_amdgcn_exp2f)
  return __builtin_amdgcn_exp2f(x);
#else
  return exp2f(x);
#endif
}

// global -> LDS direct DMA, 16B per lane. LDS dest = wave-uniform base + lane*16.
static __device__ __forceinline__ void gload_lds16(const void* g, void* l) {
  const __attribute__((address_space(1))) unsigned int* gp =
      (const __attribute__((address_space(1))) unsigned int*)(unsigned long long)(uintptr_t)g;
  __attribute__((address_space(3))) unsigned int* lp =
      (__attribute__((address_space(3))) unsigned int*)(unsigned int)(uintptr_t)l;
  __builtin_amdgcn_global_load_lds(gp, lp, 16, 0, 0);
}

// ---------------- fused prep kernel (verified R13) ----------------
// Section A [0,2880): cast hidden_states f32 -> bf16 (8 elems/thread)
// Section B [2880,7680): Wt[w][n][k] = W_w[k][n] f32 -> bf16 (32x32 LDS tiles)
// Section C [7680,49152): masks -> fragment-blocked visibility bits
__global__ void prep_fused_kernel(const float* __restrict__ x,
                                  const float* __restrict__ wq,
                                  const float* __restrict__ wk,
                                  const float* __restrict__ wv,
                                  const float* __restrict__ masks,
                                  unsigned short* __restrict__ xbf,
                                  unsigned short* __restrict__ wt,
                                  unsigned int* __restrict__ bitsF) {
  const int blk = blockIdx.x;
  const int tid = threadIdx.x;
  if (blk < 2880) {
    int i = blk * 256 + tid;
    const float4* p = (const float4*)x + (size_t)i * 2;
    float4 a = p[0], b = p[1];
    union { unsigned short u[8]; uint4 v; } pk;
    pk.u[0] = f2bf(a.x); pk.u[1] = f2bf(a.y); pk.u[2] = f2bf(a.z); pk.u[3] = f2bf(a.w);
    pk.u[4] = f2bf(b.x); pk.u[5] = f2bf(b.y); pk.u[6] = f2bf(b.z); pk.u[7] = f2bf(b.w);
    ((uint4*)xbf)[i] = pk.v;
  } else if (blk < 7680) {
    __shared__ float t[32][33];
    int idx = blk - 2880;
    int w = idx / 1600, r = idx - w * 1600;
    const float* src = (w == 0) ? wq : ((w == 1) ? wk : wv);
    int bx = (r % 40) * 32, by = (r / 40) * 32;
    int tx = tid & 31, ty = tid >> 5;     // 32 x 8
#pragma unroll
    for (int i = 0; i < 32; i += 8)
      t[ty + i][tx] = src[(size_t)(by + ty + i) * CDIM + bx + tx];
    __syncthreads();
#pragma unroll
    for (int i = 0; i < 32; i += 8)
      wt[((size_t)w * CDIM + bx + ty + i) * CDIM + by + tx] = f2bf(t[tx][ty + i]);
  } else {
    int tt = (blk - 7680) * 256 + tid;
    int word = tt >> 6, lane = tt & 63;
    int jblk = word % NKT, bi = word / NKT;          // bi = b*N + i
    float m = masks[(size_t)bi * N_TOK + jblk * 64 + lane];
    unsigned long long vis = __ballot(m > -5000.0f);
    int b = bi / N_TOK, i = bi - b * N_TOK;
    int qt = i >> 5, ql = i & 31;
    unsigned base = ((unsigned)(b * 72 + qt) * 72 + 2 * jblk) * 32 + ql;
    if (lane == 0)      bitsF[base]      = (unsigned)vis;
    else if (lane == 1) bitsF[base + 32] = (unsigned)(vis >> 32);
  }
}

// ---------------- QKV projection GEMM (verified R5) ----------------
// Staging via global_load_lds (width 16) into linear [128][64] LDS tiles with
// T2 XOR swizzle (pre-swizzled source + swizzled ds_read -- rule 21).
// Epilogue writes FRAGMENT-MAJOR buffers; Q pre-scaled by SCALE*LOG2E.
__global__ __launch_bounds__(256, 3) void gemm_qkv_kernel(
    const unsigned short* __restrict__ xbf, const unsigned short* __restrict__ wt,
    char* __restrict__ qfrag, char* __restrict__ kfrag, char* __restrict__ vfrag) {
  __shared__ unsigned short Al[128][64];   // 128B rows, linear (DMA dest)
  __shared__ unsigned short Bl[128][64];
  const int tid = threadIdx.x;
  const int lane = tid & 63, wv = tid >> 6;
  const int wm = wv >> 1, wn = wv & 1;
  const int l15 = lane & 15, l4 = lane >> 4;
  const int m0 = blockIdx.x * 128, n0 = blockIdx.y * 128;
  const int lr8 = lane >> 3;                       // 0..7: row within 8-row slab
  const int scb = ((lane & 7) * 16) ^ (lr8 << 4);  // pre-swizzled source column
  f32x4 zero = {0.f, 0.f, 0.f, 0.f};
  f32x4 acc[4][4];
#pragma unroll
  for (int mt = 0; mt < 4; mt++)
#pragma unroll
    for (int nt = 0; nt < 4; nt++) acc[mt][nt] = zero;

  for (int kk = 0; kk < CDIM; kk += 64) {
    __syncthreads();   // prior reads done before DMA overwrites
    {
      const char* asrc = (const char*)&xbf[(size_t)(m0 + wv * 32) * CDIM + kk];
      const char* bsrc = (const char*)&wt [(size_t)(n0 + wv * 32) * CDIM + kk];
#pragma unroll
      for (int i = 0; i < 4; i++) {
        gload_lds16(asrc + (size_t)(i * 8 + lr8) * (CDIM * 2) + scb, &Al[wv * 32 + i * 8][0]);
        gload_lds16(bsrc + (size_t)(i * 8 + lr8) * (CDIM * 2) + scb, &Bl[wv * 32 + i * 8][0]);
      }
    }
    __syncthreads();   // vmcnt(0) drain emitted before barrier
#pragma unroll
    for (int ks = 0; ks < 2; ks++) {
      bf16x8 af[4], bfr[4];
#pragma unroll
      for (int mt = 0; mt < 4; mt++) {
        int rA = wm * 64 + mt * 16 + l15;
        af[mt] = *(const bf16x8*)((const char*)Al + rA * 128 +
                                  ((ks * 64 + l4 * 16) ^ ((rA & 7) << 4)));
      }
#pragma unroll
      for (int nt = 0; nt < 4; nt++) {
        int rB = wn * 64 + nt * 16 + l15;
        bfr[nt] = *(const bf16x8*)((const char*)Bl + rB * 128 +
                                   ((ks * 64 + l4 * 16) ^ ((rB & 7) << 4)));
      }
#pragma unroll
      for (int mt = 0; mt < 4; mt++)
#pragma unroll
        for (int nt = 0; nt < 4; nt++)
          acc[mt][nt] = MFMA16(af[mt], bfr[nt], acc[mt][nt]);
    }
  }

  const int w_idx = n0 / CDIM;                 // 0=Q 1=K 2=V, block-uniform
  if (w_idx == 0) {
    const float qsc = (float)(0.07905694150420949 * 1.4426950408889634);
#pragma unroll
    for (int mt = 0; mt < 4; mt++)
#pragma unroll
      for (int nt = 0; nt < 4; nt++) acc[mt][nt] *= qsc;
  }
  const int cbase = n0 - w_idx * CDIM + wn * 64;
#pragma unroll
  for (int mt = 0; mt < 4; mt++) {
    const int mg = m0 + wm * 64 + mt * 16 + l4 * 4;  // token row (r=0)
    const int b = mg / N_TOK;
    const int tok = mg - b * N_TOK;
#pragma unroll
    for (int nt = 0; nt < 4; nt++) {
      const int cw = cbase + nt * 16 + l15;
      const int h = cw / DH, d = cw - h * DH;
      const size_t bh = (size_t)(b * NH + h);
      if (w_idx == 2) {
        union { unsigned short u[4]; unsigned long long v; } pk;
        pk.u[0] = f2bf(acc[mt][nt][0]); pk.u[1] = f2bf(acc[mt][nt][1]);
        pk.u[2] = f2bf(acc[mt][nt][2]); pk.u[3] = f2bf(acc[mt][nt][3]);
        char* p = vfrag + bh * FRAG_BH + (tok >> 4) * VCH_STR + (d >> 5) * 1024
                  + ((d & 31) + 32 * ((tok >> 3) & 1)) * 16 + (tok & 7) * 2;
        *(unsigned long long*)p = pk.v;
      } else {
        char* base = (w_idx == 0 ? qfrag : kfrag) + bh * FRAG_BH + (d >> 4) * 1024
                     + ((d >> 3) & 1) * 512 + (d & 7) * 2;
#pragma unroll
        for (int r = 0; r < 4; r++) {
          int t2 = tok + r;
          *(unsigned short*)(base + (t2 >> 5) * KCH_STR + (t2 & 31) * 16) =
              f2bf(acc[mt][nt][r]);
        }
      }
    }
  }
}

// ---------------- fused masked flash attention v14 ----------------
// attn8's verified body with ONE change: each wave starts its key loop at a
// UNIQUE rotation kt0 = qt (mod 72) and wraps. Online softmax is commutative
// over key-tile order, so results are identical up to fp rounding. This
// decorrelates the 72 per-bh waves that previously marched through the SAME
// K/V lines in convoy -> per-line L2 concurrency drops ~72x (the suspected
// hot-line channel-serialization wall; attn13's lockstep barrier made the
// convoy tighter and LOST 36%, supporting this mechanism).
__global__ __launch_bounds__(64, 2) void attn14_kernel(
    const char* __restrict__ qfrag, const char* __restrict__ kfrag,
    const char* __restrict__ vfrag, const unsigned int* __restrict__ bitsF,
    float* __restrict__ out) {
  __shared__ __align__(16) char smem[20480];   // [32 q][160 d] f32, XOR-swizzled
  const int lane = threadIdx.x & 63;
  const int l31 = lane & 31, h = lane >> 5;
  const int lane16 = lane * 16;
  const int id = blockIdx.x;
  const int rem = (id & 7) * 144 + (id >> 3);  // XCD-chunked remap (1152 = 8*144)
  const int bh = rem / 72, qt = rem - (rem / 72) * 72;
  const int b = bh >> 3;
  const int q0 = qt * 32;
  const int kt0 = qt;                          // unique stream rotation per wave

  const char* qfb = qfrag + (size_t)bh * FRAG_BH + (size_t)qt * KCH_STR;
  const char* kfb = kfrag + (size_t)bh * FRAG_BH;
  const char* vfb = vfrag + (size_t)bh * FRAG_BH;
  const unsigned int* bb = bitsF + (size_t)(b * 72 + qt) * 72 * 32 + l31;

  // Q fragments (pre-scaled by SCALE*LOG2E): lane-coalesced chunk reads
  bf16x8 qf[10];
#pragma unroll
  for (int ks = 0; ks < 10; ks++) qf[ks] = *(const bf16x8*)(qfb + ks * 1024 + lane16);

  const f32x16 zz = {0.f,0.f,0.f,0.f,0.f,0.f,0.f,0.f,0.f,0.f,0.f,0.f,0.f,0.f,0.f,0.f};
  f32x16 o[5];
#pragma unroll
  for (int dt = 0; dt < 5; dt++) o[dt] = zz;
  float run_m = -3.0e38f, run_l = 0.0f;

  // prologue: load rotated first tile kt0
  bf16x8 kf[10];
#pragma unroll
  for (int ks = 0; ks < 10; ks++)
    kf[ks] = *(const bf16x8*)(kfb + (size_t)kt0 * KCH_STR + ks * 1024 + lane16);

  for (int i = 0; i < 72; i++) {
    int kt = kt0 + i; if (kt >= 72) kt -= 72;            // this iter's tile
    unsigned mw = bb[kt * 32];

    // V fragments for THIS tile: issued before QK^T -> cover = QK^T + softmax
    const char* vch = vfb + (size_t)kt * KCH_STR;   // 2 V-chunks per 32-key tile
    bf16x8 va[5], vb_[5];
#pragma unroll
    for (int dt = 0; dt < 5; dt++) va[dt] = *(const bf16x8*)(vch + dt * 1024 + lane16);
#pragma unroll
    for (int dt = 0; dt < 5; dt++)
      vb_[dt] = *(const bf16x8*)(vch + 5120 + dt * 1024 + lane16);

    // S^T[key][q] = K . Q^T : lane holds 16 keys of this tile for q = q0+l31
    f32x16 s = zz;
    __builtin_amdgcn_s_setprio(1);
#pragma unroll
    for (int ks = 0; ks < 10; ks++) s = MFMA32(kf[ks], qf[ks], s);
    __builtin_amdgcn_s_setprio(0);

    // prefetch next (rotated) K tile; cover = softmax + PV
    if (i + 1 < 72) {
      int kn = kt + 1; if (kn >= 72) kn -= 72;
      const char* kr = kfb + (size_t)kn * KCH_STR;
#pragma unroll
      for (int ks = 0; ks < 10; ks++) kf[ks] = *(const bf16x8*)(kr + ks * 1024 + lane16);
    }

    // row max: pairwise tree (depth 4) then cross-half swap
    float t0 = fmaxf(fmaxf(fmaxf(s[0], s[1]), fmaxf(s[2], s[3])),
                     fmaxf(fmaxf(s[4], s[5]), fmaxf(s[6], s[7])));
    float t1 = fmaxf(fmaxf(fmaxf(s[8], s[9]), fmaxf(s[10], s[11])),
                     fmaxf(fmaxf(s[12], s[13]), fmaxf(s[14], s[15])));
    float pm = fmaxf(t0, t1);
    pm = fmaxf(pm, __shfl_xor(pm, 32));

    // defer-max (T13): skip O-rescale unless max grew by > 8 (log2 units)
    if (!__all(pm - run_m <= 8.0f)) {
      float nm = fmaxf(run_m, pm);
      float f = fexp2(run_m - nm);
      run_m = nm;
      run_l *= f;
#pragma unroll
      for (int dt = 0; dt < 5; dt++) o[dt] *= f;
    }

    float rs = 0.0f;
    unsigned pw[8];
#pragma unroll
    for (int j = 0; j < 8; j++) {
      int k0 = ((2 * j) & 3) + 8 * (j >> 1) + 4 * h;   // key of reg 2j
      float p0 = fexp2(s[2 * j] - run_m);
      float p1 = fexp2(s[2 * j + 1] - run_m);
      p0 = ((mw >> k0) & 1u) ? p0 : 0.0f;              // mask by zeroing P
      p1 = ((mw >> (k0 + 1)) & 1u) ? p1 : 0.0f;
      rs += p0 + p1;
      unsigned w;
      asm("v_cvt_pk_bf16_f32 %0, %1, %2" : "=v"(w) : "v"(p0), "v"(p1));
      pw[j] = w;
    }
    rs += __shfl_xor(rs, 32);
    run_l += rs;

    // P-frag assembly: swap(pw[0],pw[2])->(w0,w2), swap(pw[1],pw[3])->(w1,w3)
    {
      unsigned a1 = pw[0], b1 = pw[2];
      asm("v_permlane32_swap_b32 %0, %1" : "+v"(a1), "+v"(b1));
      unsigned a2 = pw[1], b2 = pw[3];
      asm("v_permlane32_swap_b32 %0, %1" : "+v"(a2), "+v"(b2));
      union { unsigned w[4]; bf16x8 v; } u;
      u.w[0] = a1; u.w[1] = a2; u.w[2] = b1; u.w[3] = b2;
      __builtin_amdgcn_s_setprio(1);
#pragma unroll
      for (int dt = 0; dt < 5; dt++) o[dt] = MFMA32(va[dt], u.v, o[dt]);
      __builtin_amdgcn_s_setprio(0);
      unsigned c1 = pw[4], d1 = pw[6];
      asm("v_permlane32_swap_b32 %0, %1" : "+v"(c1), "+v"(d1));
      unsigned c2 = pw[5], d2 = pw[7];
      asm("v_permlane32_swap_b32 %0, %1" : "+v"(c2), "+v"(d2));
      union { unsigned w[4]; bf16x8 v; } u2;
      u2.w[0] = c1; u2.w[1] = c2; u2.w[2] = d1; u2.w[3] = d2;
      __builtin_amdgcn_s_setprio(1);
#pragma unroll
      for (int dt = 0; dt < 5; dt++) o[dt] = MFMA32(vb_[dt], u2.v, o[dt]);
      __builtin_amdgcn_s_setprio(0);
    }
  }

  // ---- epilogue: normalize in-lane, transpose via LDS, coalesced store ----
  float invl = 1.0f / run_l;
#pragma unroll
  for (int dt = 0; dt < 5; dt++)
#pragma unroll
    for (int rr = 0; rr < 4; rr++) {
      float4 t;
      t.x = o[dt][4 * rr + 0] * invl;
      t.y = o[dt][4 * rr + 1] * invl;
      t.z = o[dt][4 * rr + 2] * invl;
      t.w = o[dt][4 * rr + 3] * invl;
      int d0 = dt * 32 + 8 * rr + 4 * h;
      *(float4*)(smem + l31 * 640 + ((d0 * 4) ^ ((l31 & 7) << 4))) = t;
    }
  __syncthreads();   // single wave: cheap
  // coalesced store: 32 rows x 40 float4, 20 per lane
  float* outp = out + ((size_t)b * N_TOK + q0) * CDIM + (bh & 7) * DH;
#pragma unroll
  for (int i = 0; i < 20; i++) {
    int c = i * 64 + lane;
    int q = c / 40, f = c - (c / 40) * 40;
    float4 t = *(const float4*)(smem + q * 640 + ((f * 16) ^ ((q & 7) << 4)));
    *(float4*)&outp[(size_t)q * CDIM + f * 4] = t;
  }
}

// ---------------- launcher ----------------
extern "C" void kernel_launch(void* const* d_in, const int* in_sizes, int n_in,
                              void* d_out, int out_size, void* d_ws, size_t ws_size,
                              hipStream_t stream) {
  const float* hs    = (const float*)d_in[0];
  const float* wq    = (const float*)d_in[1];
  const float* wk    = (const float*)d_in[2];
  const float* wvw   = (const float*)d_in[3];
  const float* masks = (const float*)d_in[4];
  float* out = (float*)d_out;

  char* ws = (char*)d_ws;
  unsigned short* xbf = (unsigned short*)(ws);                    // 11,796,480 B
  unsigned short* wt  = (unsigned short*)(ws + 11796480);         //  9,830,400 B
  char* qf = ws + 21626880;                                       // 11,796,480 B
  char* kf = ws + 33423360;                                       // 11,796,480 B
  char* vf = ws + 45219840;                                       // 11,796,480 B
  unsigned int* bitsF = (unsigned int*)(ws + 57016320);           //  1,327,104 B
  // total workspace: 58,343,424 B

  prep_fused_kernel<<<49152, 256, 0, stream>>>(hs, wq, wk, wvw, masks, xbf, wt, bitsF);
  gemm_qkv_kernel<<<dim3(36, 30), 256, 0, stream>>>(xbf, wt, qf, kf, vf);
  attn14_kernel<<<1152, 64, 0, stream>>>(qf, kf, vf, bitsF, out);
}

// Round 17
// 183.245 us; speedup vs baseline: 1.0211x; 1.0211x over previous
//
#include <hip/hip_runtime.h>

// Problem constants
#define N_TOK 2304
#define CDIM  1280
#define NH    8
#define DH    160
#define NKT   36          // N_TOK / 64  (u64 bitmask words per row)
#define SCALE 0.07905694150420949f   // 1/sqrt(160)
#define LOG2E 1.4426950408889634f

// Fragment-major buffer geometry (bytes)
#define FRAG_BH   737280     // 160*2304*2 per (b,h)
#define KCH_STR   10240      // 10 ks-chunks of 1KB per 32-key (or 32-q) tile
#define VCH_STR   5120       // 5 dt-chunks of 1KB per 16-key step

typedef __attribute__((ext_vector_type(8))) short bf16x8;
typedef __attribute__((ext_vector_type(4))) float f32x4;
typedef __attribute__((ext_vector_type(16))) float f32x16;

#define MFMA16(a, b, c) __builtin_amdgcn_mfma_f32_16x16x32_bf16((a), (b), (c), 0, 0, 0)
#define MFMA32(a, b, c) __builtin_amdgcn_mfma_f32_32x32x16_bf16((a), (b), (c), 0, 0, 0)

static __device__ __forceinline__ unsigned short f2bf(float f) {
  // round-to-nearest-even f32 -> bf16 (finite inputs only)
  unsigned int u = __builtin_bit_cast(unsigned int, f);
  u += 0x7fffu + ((u >> 16) & 1u);
  return (unsigned short)(u >> 16);
}

static __device__ __forceinline__ float fexp2(float x) {
#if __has_builtin(__builtin_amdgcn_exp2f)
  return __builtin_amdgcn_exp2f(x);
#else
  return exp2f(x);
#endif
}

// global -> LDS direct DMA, 16B per lane. LDS dest = wave-uniform base + lane*16.
static __device__ __forceinline__ void gload_lds16(const void* g, void* l) {
  const __attribute__((address_space(1))) unsigned int* gp =
      (const __attribute__((address_space(1))) unsigned int*)(unsigned long long)(uintptr_t)g;
  __attribute__((address_space(3))) unsigned int* lp =
      (__attribute__((address_space(3))) unsigned int*)(unsigned int)(uintptr_t)l;
  __builtin_amdgcn_global_load_lds(gp, lp, 16, 0, 0);
}

// ---------------- fused prep kernel (verified R13) ----------------
// Section A [0,2880): cast hidden_states f32 -> bf16 (8 elems/thread)
// Section B [2880,7680): Wt[w][n][k] = W_w[k][n] f32 -> bf16 (32x32 LDS tiles)
// Section C [7680,49152): masks -> fragment-blocked visibility bits
__global__ void prep_fused_kernel(const float* __restrict__ x,
                                  const float* __restrict__ wq,
                                  const float* __restrict__ wk,
                                  const float* __restrict__ wv,
                                  const float* __restrict__ masks,
                                  unsigned short* __restrict__ xbf,
                                  unsigned short* __restrict__ wt,
                                  unsigned int* __restrict__ bitsF) {
  const int blk = blockIdx.x;
  const int tid = threadIdx.x;
  if (blk < 2880) {
    int i = blk * 256 + tid;
    const float4* p = (const float4*)x + (size_t)i * 2;
    float4 a = p[0], b = p[1];
    union { unsigned short u[8]; uint4 v; } pk;
    pk.u[0] = f2bf(a.x); pk.u[1] = f2bf(a.y); pk.u[2] = f2bf(a.z); pk.u[3] = f2bf(a.w);
    pk.u[4] = f2bf(b.x); pk.u[5] = f2bf(b.y); pk.u[6] = f2bf(b.z); pk.u[7] = f2bf(b.w);
    ((uint4*)xbf)[i] = pk.v;
  } else if (blk < 7680) {
    __shared__ float t[32][33];
    int idx = blk - 2880;
    int w = idx / 1600, r = idx - w * 1600;
    const float* src = (w == 0) ? wq : ((w == 1) ? wk : wv);
    int bx = (r % 40) * 32, by = (r / 40) * 32;
    int tx = tid & 31, ty = tid >> 5;     // 32 x 8
#pragma unroll
    for (int i = 0; i < 32; i += 8)
      t[ty + i][tx] = src[(size_t)(by + ty + i) * CDIM + bx + tx];
    __syncthreads();
#pragma unroll
    for (int i = 0; i < 32; i += 8)
      wt[((size_t)w * CDIM + bx + ty + i) * CDIM + by + tx] = f2bf(t[tx][ty + i]);
  } else {
    int tt = (blk - 7680) * 256 + tid;
    int word = tt >> 6, lane = tt & 63;
    int jblk = word % NKT, bi = word / NKT;          // bi = b*N + i
    float m = masks[(size_t)bi * N_TOK + jblk * 64 + lane];
    unsigned long long vis = __ballot(m > -5000.0f);
    int b = bi / N_TOK, i = bi - b * N_TOK;
    int qt = i >> 5, ql = i & 31;
    unsigned base = ((unsigned)(b * 72 + qt) * 72 + 2 * jblk) * 32 + ql;
    if (lane == 0)      bitsF[base]      = (unsigned)vis;
    else if (lane == 1) bitsF[base + 32] = (unsigned)(vis >> 32);
  }
}

// ---------------- QKV projection GEMM (verified R5) ----------------
// Staging via global_load_lds (width 16) into linear [128][64] LDS tiles with
// T2 XOR swizzle (pre-swizzled source + swizzled ds_read -- rule 21).
// Epilogue writes FRAGMENT-MAJOR buffers; Q pre-scaled by SCALE*LOG2E.
__global__ __launch_bounds__(256, 3) void gemm_qkv_kernel(
    const unsigned short* __restrict__ xbf, const unsigned short* __restrict__ wt,
    char* __restrict__ qfrag, char* __restrict__ kfrag, char* __restrict__ vfrag) {
  __shared__ unsigned short Al[128][64];   // 128B rows, linear (DMA dest)
  __shared__ unsigned short Bl[128][64];
  const int tid = threadIdx.x;
  const int lane = tid & 63, wv = tid >> 6;
  const int wm = wv >> 1, wn = wv & 1;
  const int l15 = lane & 15, l4 = lane >> 4;
  const int m0 = blockIdx.x * 128, n0 = blockIdx.y * 128;
  const int lr8 = lane >> 3;                       // 0..7: row within 8-row slab
  const int scb = ((lane & 7) * 16) ^ (lr8 << 4);  // pre-swizzled source column
  f32x4 zero = {0.f, 0.f, 0.f, 0.f};
  f32x4 acc[4][4];
#pragma unroll
  for (int mt = 0; mt < 4; mt++)
#pragma unroll
    for (int nt = 0; nt < 4; nt++) acc[mt][nt] = zero;

  for (int kk = 0; kk < CDIM; kk += 64) {
    __syncthreads();   // prior reads done before DMA overwrites
    {
      const char* asrc = (const char*)&xbf[(size_t)(m0 + wv * 32) * CDIM + kk];
      const char* bsrc = (const char*)&wt [(size_t)(n0 + wv * 32) * CDIM + kk];
#pragma unroll
      for (int i = 0; i < 4; i++) {
        gload_lds16(asrc + (size_t)(i * 8 + lr8) * (CDIM * 2) + scb, &Al[wv * 32 + i * 8][0]);
        gload_lds16(bsrc + (size_t)(i * 8 + lr8) * (CDIM * 2) + scb, &Bl[wv * 32 + i * 8][0]);
      }
    }
    __syncthreads();   // vmcnt(0) drain emitted before barrier
#pragma unroll
    for (int ks = 0; ks < 2; ks++) {
      bf16x8 af[4], bfr[4];
#pragma unroll
      for (int mt = 0; mt < 4; mt++) {
        int rA = wm * 64 + mt * 16 + l15;
        af[mt] = *(const bf16x8*)((const char*)Al + rA * 128 +
                                  ((ks * 64 + l4 * 16) ^ ((rA & 7) << 4)));
      }
#pragma unroll
      for (int nt = 0; nt < 4; nt++) {
        int rB = wn * 64 + nt * 16 + l15;
        bfr[nt] = *(const bf16x8*)((const char*)Bl + rB * 128 +
                                   ((ks * 64 + l4 * 16) ^ ((rB & 7) << 4)));
      }
#pragma unroll
      for (int mt = 0; mt < 4; mt++)
#pragma unroll
        for (int nt = 0; nt < 4; nt++)
          acc[mt][nt] = MFMA16(af[mt], bfr[nt], acc[mt][nt]);
    }
  }

  const int w_idx = n0 / CDIM;                 // 0=Q 1=K 2=V, block-uniform
  if (w_idx == 0) {
    const float qsc = (float)(0.07905694150420949 * 1.4426950408889634);
#pragma unroll
    for (int mt = 0; mt < 4; mt++)
#pragma unroll
      for (int nt = 0; nt < 4; nt++) acc[mt][nt] *= qsc;
  }
  const int cbase = n0 - w_idx * CDIM + wn * 64;
#pragma unroll
  for (int mt = 0; mt < 4; mt++) {
    const int mg = m0 + wm * 64 + mt * 16 + l4 * 4;  // token row (r=0)
    const int b = mg / N_TOK;
    const int tok = mg - b * N_TOK;
#pragma unroll
    for (int nt = 0; nt < 4; nt++) {
      const int cw = cbase + nt * 16 + l15;
      const int h = cw / DH, d = cw - h * DH;
      const size_t bh = (size_t)(b * NH + h);
      if (w_idx == 2) {
        union { unsigned short u[4]; unsigned long long v; } pk;
        pk.u[0] = f2bf(acc[mt][nt][0]); pk.u[1] = f2bf(acc[mt][nt][1]);
        pk.u[2] = f2bf(acc[mt][nt][2]); pk.u[3] = f2bf(acc[mt][nt][3]);
        char* p = vfrag + bh * FRAG_BH + (tok >> 4) * VCH_STR + (d >> 5) * 1024
                  + ((d & 31) + 32 * ((tok >> 3) & 1)) * 16 + (tok & 7) * 2;
        *(unsigned long long*)p = pk.v;
      } else {
        char* base = (w_idx == 0 ? qfrag : kfrag) + bh * FRAG_BH + (d >> 4) * 1024
                     + ((d >> 3) & 1) * 512 + (d & 7) * 2;
#pragma unroll
        for (int r = 0; r < 4; r++) {
          int t2 = tok + r;
          *(unsigned short*)(base + (t2 >> 5) * KCH_STR + (t2 & 31) * 16) =
              f2bf(acc[mt][nt][r]);
        }
      }
    }
  }
}

// ---------------- fused masked flash attention (attn8, verified R9/R15) ----
// Barrier-free 1-wave blocks: each wave owns one 32-row q-tile, full key
// range (72 iters x 32 keys), fully-coalesced fragment-chunk loads. V for
// tile kt issued before QK^T (cover = QK^T + softmax); kf(kt+1) prefetch
// after QK^T (cover = softmax + PV). Best measured attn: ~112 us.
__global__ __launch_bounds__(64, 2) void attn8_kernel(
    const char* __restrict__ qfrag, const char* __restrict__ kfrag,
    const char* __restrict__ vfrag, const unsigned int* __restrict__ bitsF,
    float* __restrict__ out) {
  __shared__ __align__(16) char smem[20480];   // [32 q][160 d] f32, XOR-swizzled
  const int lane = threadIdx.x & 63;
  const int l31 = lane & 31, h = lane >> 5;
  const int lane16 = lane * 16;
  const int id = blockIdx.x;
  const int rem = (id & 7) * 144 + (id >> 3);  // XCD-chunked remap (1152 = 8*144)
  const int bh = rem / 72, qt = rem - (rem / 72) * 72;
  const int b = bh >> 3;
  const int q0 = qt * 32;

  const char* qfb = qfrag + (size_t)bh * FRAG_BH + (size_t)qt * KCH_STR;
  const char* kfb = kfrag + (size_t)bh * FRAG_BH;
  const char* vfb = vfrag + (size_t)bh * FRAG_BH;
  const unsigned int* bb = bitsF + (size_t)(b * 72 + qt) * 72 * 32 + l31;

  // Q fragments (pre-scaled by SCALE*LOG2E): lane-coalesced chunk reads
  bf16x8 qf[10];
#pragma unroll
  for (int ks = 0; ks < 10; ks++) qf[ks] = *(const bf16x8*)(qfb + ks * 1024 + lane16);

  const f32x16 zz = {0.f,0.f,0.f,0.f,0.f,0.f,0.f,0.f,0.f,0.f,0.f,0.f,0.f,0.f,0.f,0.f};
  f32x16 o[5];
#pragma unroll
  for (int dt = 0; dt < 5; dt++) o[dt] = zz;
  float run_m = -3.0e38f, run_l = 0.0f;

  bf16x8 kf[10];
#pragma unroll
  for (int ks = 0; ks < 10; ks++) kf[ks] = *(const bf16x8*)(kfb + ks * 1024 + lane16);

  for (int kt = 0; kt < 72; kt++) {
    unsigned mw = bb[kt * 32];

    // V fragments for THIS tile: issued before QK^T -> cover = QK^T + softmax
    const char* vch = vfb + (size_t)kt * KCH_STR;   // 2 V-chunks per 32-key tile
    bf16x8 va[5], vb_[5];
#pragma unroll
    for (int dt = 0; dt < 5; dt++) va[dt] = *(const bf16x8*)(vch + dt * 1024 + lane16);
#pragma unroll
    for (int dt = 0; dt < 5; dt++)
      vb_[dt] = *(const bf16x8*)(vch + 5120 + dt * 1024 + lane16);

    // S^T[key][q] = K . Q^T : lane holds 16 keys of this tile for q = q0+l31
    f32x16 s = zz;
    __builtin_amdgcn_s_setprio(1);
#pragma unroll
    for (int ks = 0; ks < 10; ks++) s = MFMA32(kf[ks], qf[ks], s);
    __builtin_amdgcn_s_setprio(0);

    // prefetch next K tile (after QK^T consumed kf; cover = softmax + PV)
    if (kt + 1 < 72) {
      const char* kr = kfb + (size_t)(kt + 1) * KCH_STR;
#pragma unroll
      for (int ks = 0; ks < 10; ks++) kf[ks] = *(const bf16x8*)(kr + ks * 1024 + lane16);
    }

    // row max: pairwise tree (depth 4) then cross-half swap
    float t0 = fmaxf(fmaxf(fmaxf(s[0], s[1]), fmaxf(s[2], s[3])),
                     fmaxf(fmaxf(s[4], s[5]), fmaxf(s[6], s[7])));
    float t1 = fmaxf(fmaxf(fmaxf(s[8], s[9]), fmaxf(s[10], s[11])),
                     fmaxf(fmaxf(s[12], s[13]), fmaxf(s[14], s[15])));
    float pm = fmaxf(t0, t1);
    pm = fmaxf(pm, __shfl_xor(pm, 32));

    // defer-max (T13): skip O-rescale unless max grew by > 8 (log2 units)
    if (!__all(pm - run_m <= 8.0f)) {
      float nm = fmaxf(run_m, pm);
      float f = fexp2(run_m - nm);
      run_m = nm;
      run_l *= f;
#pragma unroll
      for (int dt = 0; dt < 5; dt++) o[dt] *= f;
    }

    float rs = 0.0f;
    unsigned pw[8];
#pragma unroll
    for (int i = 0; i < 8; i++) {
      int k0 = ((2 * i) & 3) + 8 * (i >> 1) + 4 * h;   // key of reg 2i
      float p0 = fexp2(s[2 * i] - run_m);
      float p1 = fexp2(s[2 * i + 1] - run_m);
      p0 = ((mw >> k0) & 1u) ? p0 : 0.0f;              // mask by zeroing P
      p1 = ((mw >> (k0 + 1)) & 1u) ? p1 : 0.0f;
      rs += p0 + p1;
      unsigned w;
      asm("v_cvt_pk_bf16_f32 %0, %1, %2" : "=v"(w) : "v"(p0), "v"(p1));
      pw[i] = w;
    }
    rs += __shfl_xor(rs, 32);
    run_l += rs;

    // P-frag assembly: swap(pw[0],pw[2])->(w0,w2), swap(pw[1],pw[3])->(w1,w3)
    {
      unsigned a1 = pw[0], b1 = pw[2];
      asm("v_permlane32_swap_b32 %0, %1" : "+v"(a1), "+v"(b1));
      unsigned a2 = pw[1], b2 = pw[3];
      asm("v_permlane32_swap_b32 %0, %1" : "+v"(a2), "+v"(b2));
      union { unsigned w[4]; bf16x8 v; } u;
      u.w[0] = a1; u.w[1] = a2; u.w[2] = b1; u.w[3] = b2;
      __builtin_amdgcn_s_setprio(1);
#pragma unroll
      for (int dt = 0; dt < 5; dt++) o[dt] = MFMA32(va[dt], u.v, o[dt]);
      __builtin_amdgcn_s_setprio(0);
      unsigned c1 = pw[4], d1 = pw[6];
      asm("v_permlane32_swap_b32 %0, %1" : "+v"(c1), "+v"(d1));
      unsigned c2 = pw[5], d2 = pw[7];
      asm("v_permlane32_swap_b32 %0, %1" : "+v"(c2), "+v"(d2));
      union { unsigned w[4]; bf16x8 v; } u2;
      u2.w[0] = c1; u2.w[1] = c2; u2.w[2] = d1; u2.w[3] = d2;
      __builtin_amdgcn_s_setprio(1);
#pragma unroll
      for (int dt = 0; dt < 5; dt++) o[dt] = MFMA32(vb_[dt], u2.v, o[dt]);
      __builtin_amdgcn_s_setprio(0);
    }
  }

  // ---- epilogue: normalize in-lane, transpose via LDS, coalesced store ----
  float invl = 1.0f / run_l;
#pragma unroll
  for (int dt = 0; dt < 5; dt++)
#pragma unroll
    for (int rr = 0; rr < 4; rr++) {
      float4 t;
      t.x = o[dt][4 * rr + 0] * invl;
      t.y = o[dt][4 * rr + 1] * invl;
      t.z = o[dt][4 * rr + 2] * invl;
      t.w = o[dt][4 * rr + 3] * invl;
      int d0 = dt * 32 + 8 * rr + 4 * h;
      *(float4*)(smem + l31 * 640 + ((d0 * 4) ^ ((l31 & 7) << 4))) = t;
    }
  __syncthreads();   // single wave: cheap
  // coalesced store: 32 rows x 40 float4, 20 per lane
  float* outp = out + ((size_t)b * N_TOK + q0) * CDIM + (bh & 7) * DH;
#pragma unroll
  for (int i = 0; i < 20; i++) {
    int c = i * 64 + lane;
    int q = c / 40, f = c - (c / 40) * 40;
    float4 t = *(const float4*)(smem + q * 640 + ((f * 16) ^ ((q & 7) << 4)));
    *(float4*)&outp[(size_t)q * CDIM + f * 4] = t;
  }
}

// ---------------- launcher ----------------
extern "C" void kernel_launch(void* const* d_in, const int* in_sizes, int n_in,
                              void* d_out, int out_size, void* d_ws, size_t ws_size,
                              hipStream_t stream) {
  const float* hs    = (const float*)d_in[0];
  const float* wq    = (const float*)d_in[1];
  const float* wk    = (const float*)d_in[2];
  const float* wvw   = (const float*)d_in[3];
  const float* masks = (const float*)d_in[4];
  float* out = (float*)d_out;

  char* ws = (char*)d_ws;
  unsigned short* xbf = (unsigned short*)(ws);                    // 11,796,480 B
  unsigned short* wt  = (unsigned short*)(ws + 11796480);         //  9,830,400 B
  char* qf = ws + 21626880;                                       // 11,796,480 B
  char* kf = ws + 33423360;                                       // 11,796,480 B
  char* vf = ws + 45219840;                                       // 11,796,480 B
  unsigned int* bitsF = (unsigned int*)(ws + 57016320);           //  1,327,104 B
  // total workspace: 58,343,424 B

  prep_fused_kernel<<<49152, 256, 0, stream>>>(hs, wq, wk, wvw, masks, xbf, wt, bitsF);
  gemm_qkv_kernel<<<dim3(36, 30), 256, 0, stream>>>(xbf, wt, qf, kf, vf);
  attn8_kernel<<<1152, 64, 0, stream>>>(qf, kf, vf, bitsF, out);
}